// Round 2
// baseline (312.675 us; speedup 1.0000x reference)
//
#include <hip/hip_runtime.h>
#include <stdint.h>

// SNN membrane scan + spike + double-cumsum, fused single pass.
// 16384 channels -> 256 blocks x 64 threads = 1 wave/CU (structural: exact
// sequential fmaf chain in T cannot be split without bit-exactness risk at the
// spike threshold). Latency hiding at 1 wave/CU via async global->LDS staging:
// __builtin_amdgcn_global_load_lds consumes NO VGPRs per in-flight load, and
// the compiler emits no waitcnt for it -> manual vmcnt pipeline, depth 4
// chunks (32 loads = 8 KB in flight/CU; need ~4.6 KB for the 6.3 TB/s share).

#define T_LEN  1024
#define N_IN   512
#define BN     16384          // BATCH * N_IN
#define CT     8              // timesteps per chunk
#define NCHUNK (T_LEN / CT)   // 128
#define NSLOT  6              // LDS ring slots (> DEPTH+1)
#define DEPTH  4              // chunks prefetched ahead

#define AS_GLOBAL(p) (const __attribute__((address_space(1))) void*)(p)
#define AS_LDS(p)    (__attribute__((address_space(3))) void*)(p)

__global__ __launch_bounds__(64, 1) void snn_scan(
        const float* __restrict__ cur, const float* __restrict__ beta,
        const float* __restrict__ vini, const float* __restrict__ vth,
        float* __restrict__ gz, float* __restrict__ zo, float* __restrict__ ml)
{
    // bc/bv[slot][t][lane]: global_load_lds writes wave-uniform base + lane*4,
    // which is exactly [slot][t][0..63] (contiguous 256 B per instruction).
    __shared__ float bc[NSLOT][CT][64];
    __shared__ float bv[NSLOT][CT][64];

    const int tid = threadIdx.x;
    const int ch  = blockIdx.x * 64 + tid;          // channel = b*N + n
    const float bta = beta[ch & (N_IN - 1)];
    float m = vini[ch];
    int c1 = 0, z = 0;

    const float* cp = cur + ch;   // per-lane global base (lane-contiguous)
    const float* vp = vth + ch;
    float* gp = gz + ch;
    float* zp = zo + ch;

    auto issue = [&](int chunk) {
        const int slot = chunk % NSLOT;
        const float* c0 = cp + (size_t)chunk * CT * BN;
        const float* v0 = vp + (size_t)chunk * CT * BN;
#pragma unroll
        for (int t = 0; t < CT; ++t) {
            __builtin_amdgcn_global_load_lds(AS_GLOBAL(c0 + (size_t)t * BN),
                                             AS_LDS(&bc[slot][t][0]), 4, 0, 0);
            __builtin_amdgcn_global_load_lds(AS_GLOBAL(v0 + (size_t)t * BN),
                                             AS_LDS(&bv[slot][t][0]), 4, 0, 0);
        }
    };

    issue(0); issue(1); issue(2); issue(3);

    for (int chunk = 0; chunk < NCHUNK; ++chunk) {
        if (chunk + DEPTH < NCHUNK) issue(chunk + DEPTH);
        // Guarantee chunk's 16 lds-loads are complete: ops issued after them =
        // 4 chunks of loads (64) + interleaved stores (>63, in-order vmcnt),
        // plus this explicit wait as compiler fence + belt-and-suspenders.
        asm volatile("s_waitcnt vmcnt(48)" ::: "memory");
        const int slot = chunk % NSLOT;
#pragma unroll
        for (int t = 0; t < CT; ++t) {
            const float c = bc[slot][t][tid];
            const float v = bv[slot][t][tid];
            m = fmaf(bta, m, c);               // exact reference chain order
            c1 += (m >= v) ? 1 : 0;            // Heaviside(m - vth), exact equiv
            z  += c1;                          // double cumsum, exact in int
            const size_t off = (size_t)(chunk * CT + t) * BN;
            gp[off] = (z == 1) ? 1.0f : 0.0f;
            zp[off] = (float)z;
        }
    }
    ml[ch] = m;   // m_last (B,N)
}

extern "C" void kernel_launch(void* const* d_in, const int* in_sizes, int n_in,
                              void* d_out, int out_size, void* d_ws, size_t ws_size,
                              hipStream_t stream) {
    const float* cur  = (const float*)d_in[0];   // (T,B,N) fp32
    const float* beta = (const float*)d_in[1];   // (N,)
    const float* vini = (const float*)d_in[2];   // (B,N)
    const float* vth  = (const float*)d_in[3];   // (T,B,N)
    float* gz = (float*)d_out;                   // (T,B,N)
    float* zo = gz + (size_t)T_LEN * BN;         // (T,B,N)
    float* ml = zo + (size_t)T_LEN * BN;         // (B,N)
    snn_scan<<<BN / 64, 64, 0, stream>>>(cur, beta, vini, vth, gz, zo, ml);
}